// Round 12
// baseline (137.816 us; speedup 1.0000x reference)
//
#include <hip/hip_runtime.h>

#define BB 16      // batch
#define SS 48      // seq len
#define VV 16000   // vocab
#define DD 128     // embed
#define NC (DD / 4)        // 32 float4 per row
#define TPW 5              // 16-row tiles per wave
#define NTH 256            // 4 waves per block
#define TGRP (4 * TPW)     // tiles per block = 20
#define BPS (VV / 16 / TGRP)   // 50 blocks per s (50*20*16 = 16000 exactly)

constexpr float EPS   = 1e-8f;
constexpr float SCALE = 10.0f;

typedef __attribute__((ext_vector_type(8))) short bf16x8;
typedef __attribute__((ext_vector_type(4))) float f32x4;

__device__ __forceinline__ unsigned short f2bf_rne(float x) {
    union { float f; unsigned u; } v; v.f = x;
    unsigned r = v.u + 0x7fffu + ((v.u >> 16) & 1u);   // round-to-nearest-even
    return (unsigned short)(r >> 16);
}

// Kernel 1 (verified R2-R11): per-batch causal prefix context, f32-normalized,
// emitted as bf16 ctx_bf[S][B][D]. One block = one batch, 64 threads.
__global__ __launch_bounds__(64) void ctx_kernel(
    const int*      __restrict__ tokens,   // [B,S]
    const float*    __restrict__ scalars,  // [S,V]
    const float*    __restrict__ wvecs,    // [S,V,D]
    unsigned short* __restrict__ ctx_bf)   // [S,B,D] bf16
{
    const int b    = blockIdx.x;
    const int lane = threadIdx.x;  // 0..63

    float a[SS], w0[SS], w1[SS];
    #pragma unroll
    for (int s = 0; s < SS; ++s) {
        const int tok = tokens[b * SS + s];
        a[s] = scalars[(size_t)s * VV + tok];
        const float* wp = wvecs + ((size_t)s * VV + tok) * DD;
        w0[s] = wp[lane];
        w1[s] = wp[lane + 64];
    }

    float run0 = 0.f, run1 = 0.f;
    #pragma unroll
    for (int s = 0; s < SS; ++s) {
        float p = fmaf(run0, run0, run1 * run1);
        #pragma unroll
        for (int off = 32; off > 0; off >>= 1)
            p += __shfl_xor(p, off);
        const float denom = fmaxf(sqrtf(p), EPS);  // torch F.normalize semantics
        unsigned short* o = ctx_bf + ((size_t)s * BB + b) * DD;
        o[lane]      = f2bf_rne(run0 / denom);
        o[lane + 64] = f2bf_rne(run1 / denom);
        run0 = fmaf(a[s], w0[s], run0);   // position s contributes to positions > s
        run1 = fmaf(a[s], w1[s], run1);
    }
}

// Kernel 2: out[b,s,v] = SCALE * dot(ctx_n, emb[s,v,:]) / max(||emb[s,v,:]||,eps)
//
// R11 post-mortem: barrier-coupled burst staging capped reads at ~3.7 TB/s.
// This version has NO LDS and NO barriers in the hot path: each WAVE
// independently processes 16-row v-tiles, loading MFMA B-fragments straight
// from global (lane (kg,c): rows vbase+c, f32 slots sl*8+kg*2+{0,1} — per
// instruction 16 rows x 32B inside one contiguous 8KB region). Norm from the
// f32 values (squares + shfl_xor 16/32), convert to bf16 in-register, 4
// mfma_16x16x32_bf16, scaled store. Depth-1 prefetch, named A/B buffers.
__global__ __launch_bounds__(NTH) void logits_kernel(
    const unsigned short* __restrict__ ctx_bf,  // [S,B,D] bf16
    const float*          __restrict__ emb,     // [S,V,D] f32
    float*                __restrict__ out)     // [B,S,V] f32
{
    const int s    = blockIdx.y;
    const int tid  = threadIdx.x;   // 0..255
    const int lane = tid & 63;
    const int wv   = tid >> 6;      // wave 0..3
    const int c    = lane & 15;     // fragment column: v-row in tile / A-row (batch)
    const int kg   = lane >> 4;     // k-group 0..3

    // A-fragments: ctx bf16 (8 KB per s, L2-resident). Verified R10/R11.
    bf16x8 afrag[4];
    {
        const unsigned short* cb = ctx_bf + ((size_t)s * BB + c) * DD + kg * 8;
        #pragma unroll
        for (int sl = 0; sl < 4; ++sl)
            afrag[sl] = *(const bf16x8*)(cb + sl * 32);
    }

    const int T0 = blockIdx.x * TGRP + wv * TPW;   // this wave's first tile
    // per-lane base: row (T0*16 + c), f32x4 slot kg*2. Advance 512 float4/tile.
    const float4* ebase = (const float4*)emb
                        + ((size_t)s * VV + (size_t)T0 * 16 + c) * NC + kg * 2;

#define LOADT(BUF, t)                                            \
    {                                                            \
        _Pragma("unroll")                                        \
        for (int sl = 0; sl < 4; ++sl) {                         \
            BUF[sl * 2 + 0] = ebase[(t) * 512 + sl * 8 + 0];     \
            BUF[sl * 2 + 1] = ebase[(t) * 512 + sl * 8 + 1];     \
        }                                                        \
    }

#define COMPUTE(BUF, t)                                                       \
    {                                                                         \
        float pn = 0.f;                                                       \
        _Pragma("unroll")                                                     \
        for (int i = 0; i < 8; ++i) {                                         \
            pn = fmaf(BUF[i].x, BUF[i].x, pn);                                \
            pn = fmaf(BUF[i].y, BUF[i].y, pn);                                \
            pn = fmaf(BUF[i].z, BUF[i].z, pn);                                \
            pn = fmaf(BUF[i].w, BUF[i].w, pn);                                \
        }                                                                     \
        pn += __shfl_xor(pn, 16);                                             \
        pn += __shfl_xor(pn, 32);   /* full ||row||^2 in every lane */        \
        f32x4 acc = {0.f, 0.f, 0.f, 0.f};                                     \
        _Pragma("unroll")                                                     \
        for (int sl = 0; sl < 4; ++sl) {                                      \
            union { unsigned u[4]; bf16x8 v; } bf;                            \
            bf.u[0] = ((unsigned)f2bf_rne(BUF[sl*2+0].y) << 16) | f2bf_rne(BUF[sl*2+0].x); \
            bf.u[1] = ((unsigned)f2bf_rne(BUF[sl*2+0].w) << 16) | f2bf_rne(BUF[sl*2+0].z); \
            bf.u[2] = ((unsigned)f2bf_rne(BUF[sl*2+1].y) << 16) | f2bf_rne(BUF[sl*2+1].x); \
            bf.u[3] = ((unsigned)f2bf_rne(BUF[sl*2+1].w) << 16) | f2bf_rne(BUF[sl*2+1].z); \
            acc = __builtin_amdgcn_mfma_f32_16x16x32_bf16(afrag[sl], bf.v, acc, 0, 0, 0); \
        }                                                                     \
        const float f = SCALE / fmaxf(sqrtf(pn), EPS);                        \
        const int v = (T0 + (t)) * 16 + c;                                    \
        _Pragma("unroll")                                                     \
        for (int reg = 0; reg < 4; ++reg)                                     \
            out[((size_t)(kg * 4 + reg) * SS + s) * VV + v] = acc[reg] * f;   \
    }

    float4 A[8], B[8];
    LOADT(A, 0);
    LOADT(B, 1); COMPUTE(A, 0);
    LOADT(A, 2); COMPUTE(B, 1);
    LOADT(B, 3); COMPUTE(A, 2);
    LOADT(A, 4); COMPUTE(B, 3);
    COMPUTE(A, 4);

#undef LOADT
#undef COMPUTE
}

extern "C" void kernel_launch(void* const* d_in, const int* in_sizes, int n_in,
                              void* d_out, int out_size, void* d_ws, size_t ws_size,
                              hipStream_t stream) {
    const int*      tokens  = (const int*)d_in[0];
    const float*    scalars = (const float*)d_in[1];
    const float*    wvecs   = (const float*)d_in[2];
    const float*    emb     = (const float*)d_in[3];
    float*          out     = (float*)d_out;
    unsigned short* ctx_bf  = (unsigned short*)d_ws;   // S*B*D*2 = 196,608 bytes

    ctx_kernel<<<dim3(BB), dim3(64), 0, stream>>>(tokens, scalars, wvecs, ctx_bf);

    dim3 grid(BPS, SS);   // (50, 48) = 2400 blocks, 256 threads, no LDS
    logits_kernel<<<grid, dim3(NTH), 0, stream>>>(ctx_bf, emb, out);
}

// Round 14
// 100.408 us; speedup vs baseline: 1.3726x; 1.3726x over previous
//
#include <hip/hip_runtime.h>

#define BB 16      // batch
#define SS 48      // seq len
#define VV 16000   // vocab
#define DD 128     // embed
#define TVR 128    // v-rows per block tile
#define NTH 256    // threads per block (4 waves)

constexpr float EPS   = 1e-8f;
constexpr float SCALE = 10.0f;

typedef __attribute__((ext_vector_type(8))) short bf16x8;
typedef __attribute__((ext_vector_type(4))) float f32x4;

__device__ __forceinline__ unsigned short f2bf_rne(float x) {
    union { float f; unsigned u; } v; v.f = x;
    unsigned r = v.u + 0x7fffu + ((v.u >> 16) & 1u);   // round-to-nearest-even
    return (unsigned short)(r >> 16);
}

// Kernel 1 (verified R2-R12): per-batch causal prefix context, f32-normalized,
// emitted as bf16 ctx_bf[S][B][D]. One block = one batch, 64 threads.
__global__ __launch_bounds__(64) void ctx_kernel(
    const int*      __restrict__ tokens,   // [B,S]
    const float*    __restrict__ scalars,  // [S,V]
    const float*    __restrict__ wvecs,    // [S,V,D]
    unsigned short* __restrict__ ctx_bf)   // [S,B,D] bf16
{
    const int b    = blockIdx.x;
    const int lane = threadIdx.x;  // 0..63

    float a[SS], w0[SS], w1[SS];
    #pragma unroll
    for (int s = 0; s < SS; ++s) {
        const int tok = tokens[b * SS + s];
        a[s] = scalars[(size_t)s * VV + tok];
        const float* wp = wvecs + ((size_t)s * VV + tok) * DD;
        w0[s] = wp[lane];
        w1[s] = wp[lane + 64];
    }

    float run0 = 0.f, run1 = 0.f;
    #pragma unroll
    for (int s = 0; s < SS; ++s) {
        float p = fmaf(run0, run0, run1 * run1);
        #pragma unroll
        for (int off = 32; off > 0; off >>= 1)
            p += __shfl_xor(p, off);
        const float denom = fmaxf(sqrtf(p), EPS);  // torch F.normalize semantics
        unsigned short* o = ctx_bf + ((size_t)s * BB + b) * DD;
        o[lane]      = f2bf_rne(run0 / denom);
        o[lane + 64] = f2bf_rne(run1 / denom);
        run0 = fmaf(a[s], w0[s], run0);   // position s contributes to positions > s
        run1 = fmaf(a[s], w1[s], run1);
    }
}

// Kernel 2 (R10 structure — best at 126 us — with ONE change: nontemporal
// loads on the emb stream and nontemporal stores on out. emb has zero reuse,
// so L2 allocation only thrashes; out stores shouldn't RFO/pollute).
__global__ __launch_bounds__(NTH) void logits_kernel(
    const unsigned short* __restrict__ ctx_bf,  // [S,B,D] bf16
    const float*          __restrict__ emb,     // [S,V,D] f32
    float*                __restrict__ out)     // [B,S,V] f32
{
    const int s    = blockIdx.y;
    const int v0   = blockIdx.x * TVR;
    const int tid  = threadIdx.x;      // 0..255
    const int lane = tid & 63;
    const int wv   = tid >> 6;         // wave 0..3

    __shared__ unsigned short eL[TVR * DD];  // 32 KB bf16 tile (swizzled 16B slots)
    __shared__ float nrm[TVR];               // row norms^2

    // ---- stage: dense coalesced f32 loads, NONTEMPORAL (no L2 allocate).
    // f32x4 is a true clang vector type -> accepted by the builtin.
    const f32x4* src = (const f32x4*)(emb + ((size_t)s * VV + v0) * DD);
    f32x4 g[16];
    #pragma unroll
    for (int i = 0; i < 16; ++i)
        g[i] = __builtin_nontemporal_load(&src[tid + i * NTH]);

    // convert to bf16, write 8B granules; 16B-slot index XOR-swizzled by row&7
    const int slot4  = tid & 31;       // float4-slot (4 f32)
    const int slot16 = slot4 >> 1;     // 16B slot (8 bf16)
    const int hw     = slot4 & 1;      // half within 16B slot
    #pragma unroll
    for (int i = 0; i < 16; ++i) {
        const int row = (tid >> 5) + i * 8;
        const unsigned lo = ((unsigned)f2bf_rne(g[i][1]) << 16) | f2bf_rne(g[i][0]);
        const unsigned hi = ((unsigned)f2bf_rne(g[i][3]) << 16) | f2bf_rne(g[i][2]);
        unsigned* dst = (unsigned*)&eL[row * DD + ((slot16 ^ (row & 7)) << 3) + (hw << 2)];
        dst[0] = lo;
        dst[1] = hi;
    }
    __syncthreads();

    // ---- norms (f32 arithmetic over the bf16 tile): thread owns half a row
    {
        const int row = tid >> 1, half = tid & 1;
        float pn = 0.f;
        #pragma unroll
        for (int j = 0; j < 8; ++j) {
            const int s16 = half * 8 + j;
            const bf16x8 hh = *(const bf16x8*)&eL[row * DD + ((s16 ^ (row & 7)) << 3)];
            #pragma unroll
            for (int c = 0; c < 8; ++c) {
                union { unsigned u; float f; } t;
                t.u = ((unsigned)(unsigned short)hh[c]) << 16;
                pn = fmaf(t.f, t.f, pn);
            }
        }
        pn += __shfl_xor(pn, 1);       // partner half of same row
        if (half == 0) nrm[row] = pn;
    }
    __syncthreads();

    // ---- A-frags: ctx bf16 (L2-resident, reused by 125 blocks) — cached loads.
    bf16x8 afrag[4];
    {
        const unsigned short* cb = ctx_bf + ((size_t)s * BB + (lane & 15)) * DD + (lane >> 4) * 8;
        #pragma unroll
        for (int sl = 0; sl < 4; ++sl)
            afrag[sl] = *(const bf16x8*)(cb + sl * 32);
    }

    // ---- MFMA: wave wv owns 16-row groups 2wv and 2wv+1.
    f32x4 acc0 = {0.f, 0.f, 0.f, 0.f};
    f32x4 acc1 = {0.f, 0.f, 0.f, 0.f};
    const int r0 = (wv * 2) * 16 + (lane & 15);
    const int r1 = (wv * 2 + 1) * 16 + (lane & 15);
    #pragma unroll
    for (int sl = 0; sl < 4; ++sl) {
        const int q = sl * 4 + (lane >> 4);
        const bf16x8 b0 = *(const bf16x8*)&eL[r0 * DD + ((q ^ (r0 & 7)) << 3)];
        const bf16x8 b1 = *(const bf16x8*)&eL[r1 * DD + ((q ^ (r1 & 7)) << 3)];
        acc0 = __builtin_amdgcn_mfma_f32_16x16x32_bf16(afrag[sl], b0, acc0, 0, 0, 0);
        acc1 = __builtin_amdgcn_mfma_f32_16x16x32_bf16(afrag[sl], b1, acc1, 0, 0, 0);
    }

    // ---- store: NONTEMPORAL (no RFO, no L2 pollution).
    const float f0 = SCALE / fmaxf(sqrtf(nrm[r0]), EPS);  // F.normalize semantics
    const float f1 = SCALE / fmaxf(sqrtf(nrm[r1]), EPS);
    const int va = v0 + r0;
    const int vb = v0 + r1;
    #pragma unroll
    for (int reg = 0; reg < 4; ++reg) {
        const int b = (lane >> 4) * 4 + reg;
        __builtin_nontemporal_store(acc0[reg] * f0, &out[((size_t)b * SS + s) * VV + va]);
        __builtin_nontemporal_store(acc1[reg] * f1, &out[((size_t)b * SS + s) * VV + vb]);
    }
}

extern "C" void kernel_launch(void* const* d_in, const int* in_sizes, int n_in,
                              void* d_out, int out_size, void* d_ws, size_t ws_size,
                              hipStream_t stream) {
    const int*      tokens  = (const int*)d_in[0];
    const float*    scalars = (const float*)d_in[1];
    const float*    wvecs   = (const float*)d_in[2];
    const float*    emb     = (const float*)d_in[3];
    float*          out     = (float*)d_out;
    unsigned short* ctx_bf  = (unsigned short*)d_ws;   // S*B*D*2 = 196,608 bytes

    ctx_kernel<<<dim3(BB), dim3(64), 0, stream>>>(tokens, scalars, wvecs, ctx_bf);

    dim3 grid(VV / TVR, SS);   // (125, 48) = 6000 blocks
    logits_kernel<<<grid, dim3(NTH), 0, stream>>>(ctx_bf, emb, out);
}